// Round 1
// baseline (1178.898 us; speedup 1.0000x reference)
//
#include <hip/hip_runtime.h>

// Upsampling 2x nearest-neighbor: (16,64,256,256) fp32 -> (16,64,512,512) fp32.
// Pure data movement, HBM-bound. One thread per input float2; emits one float4
// (x,x,y,y) stored to two output rows. Coalesced 8B loads, coalesced 16B
// full-cacheline stores (no read-for-ownership).

constexpr int B = 16;
constexpr int C = 64;
constexpr int H = 256;
constexpr int W = 256;
constexpr int SCALE = 2;

// Input viewed as float2: (B*C*H) rows x (W/2) cols.
constexpr int IN_VEC_PER_ROW = W / 2;             // 128 (power of two)
constexpr long long N_IN_VEC = (long long)B * C * H * IN_VEC_PER_ROW; // 33,554,432
// Output viewed as float4: pitch per output row.
constexpr int OUT_VEC_PER_ROW = (W * SCALE) / 4;  // 128

__global__ __launch_bounds__(256)
void Upsampling_68882685493276_kernel(const float2* __restrict__ in,
                                      float4* __restrict__ out) {
    long long t = (long long)blockIdx.x * blockDim.x + threadIdx.x;
    if (t >= N_IN_VEC) return;

    int col = (int)(t & (IN_VEC_PER_ROW - 1)); // t % 128
    long long r = t >> 7;                      // input row index across B*C*H

    float2 v = in[t];
    float4 o = make_float4(v.x, v.x, v.y, v.y);

    long long orow = r * SCALE;
    out[orow * OUT_VEC_PER_ROW + col]       = o;
    out[(orow + 1) * OUT_VEC_PER_ROW + col] = o;
}

extern "C" void kernel_launch(void* const* d_in, const int* in_sizes, int n_in,
                              void* d_out, int out_size, void* d_ws, size_t ws_size,
                              hipStream_t stream) {
    const float2* in = (const float2*)d_in[0];
    float4* out = (float4*)d_out;

    const int block = 256;
    const long long grid = (N_IN_VEC + block - 1) / block; // 131,072
    Upsampling_68882685493276_kernel<<<dim3((unsigned)grid), dim3(block), 0, stream>>>(in, out);
}